// Round 1
// baseline (1251.538 us; speedup 1.0000x reference)
//
// Fused SDPA (B=32, N=2048, D=128, fp32 in/out) for gfx950.
// d_out = [output: 32*2048*128 f32][attn: 32*2048*2048 f32]
// Two passes over K per Q-block: pass A = softmax denominators, pass B =
// normalized P -> global attn (+ nontemporal) and PV accumulation via MFMA.
#include <hip/hip_runtime.h>

#define NQ     2048
#define DDIM   128
#define NB     32
#define KBLK   64
#define NT     (NQ / KBLK)      // 32 K-tiles
#define NWAVE  8
#define QW     32               // q rows per wave
#define QBLK   (NWAVE * QW)     // 256 q rows per block

typedef __attribute__((ext_vector_type(8)))  short          short8;
typedef __attribute__((ext_vector_type(4)))  float          f32x4;
typedef __attribute__((ext_vector_type(16))) float          f32x16;
typedef __attribute__((ext_vector_type(4)))  unsigned short us4;

static constexpr float SEXP = 1.4426950408889634f / 11.313708498984761f; // log2(e)/temperature

__device__ __forceinline__ unsigned short f2b(float f) {   // f32 -> bf16 (RNE)
  unsigned u = __builtin_bit_cast(unsigned, f);
  u += 0x7fffu + ((u >> 16) & 1u);
  return (unsigned short)(u >> 16);
}
__device__ __forceinline__ unsigned cvtpk(float lo, float hi) {
  unsigned r;
  asm volatile("v_cvt_pk_bf16_f32 %0, %1, %2" : "=v"(r) : "v"(lo), "v"(hi));
  return r;
}
__device__ __forceinline__ void plswap(unsigned &a, unsigned &b) {
  asm volatile("v_permlane32_swap_b32 %0, %1" : "+v"(a), "+v"(b));
}
__device__ __forceinline__ f32x16 zero16() {
  f32x16 z;
#pragma unroll
  for (int i = 0; i < 16; i++) z[i] = 0.0f;
  return z;
}

// PV step: build A-operand (P rows, bf16) for k-step `tt` from 8 exp values,
// then accumulate o[df] += P * V using VT (transposed V) in LDS.
template <int RB>
__device__ __forceinline__ void pv_step(const float (&e)[16], int tt, int l31, int h,
                                        const unsigned short *__restrict__ VTl,
                                        f32x16 (&o)[4]) {
  unsigned a0 = cvtpk(e[RB + 0], e[RB + 1]);
  unsigned a1 = cvtpk(e[RB + 2], e[RB + 3]);
  unsigned b0 = cvtpk(e[RB + 4], e[RB + 5]);
  unsigned b1 = cvtpk(e[RB + 6], e[RB + 7]);
  plswap(a0, b0);   // a0 -> word0 (j = tt*16+8h+{0,1}), b0 -> word2 ({4,5})
  plswap(a1, b1);   // a1 -> word1 ({2,3}),             b1 -> word3 ({6,7})
  union { short8 s; unsigned u[4]; } pa;
  pa.u[0] = a0; pa.u[1] = a1; pa.u[2] = b0; pa.u[3] = b1;
#pragma unroll
  for (int df = 0; df < 4; df++) {
    const int d = df * 32 + l31;
    union { short8 s; us4 q[2]; } vf;
    vf.q[0] = *(const us4 *)&VTl[d * 64 + (((tt * 16 + h * 8) + 0) ^ ((d & 15) << 2))];
    vf.q[1] = *(const us4 *)&VTl[d * 64 + (((tt * 16 + h * 8) + 4) ^ ((d & 15) << 2))];
    o[df] = __builtin_amdgcn_mfma_f32_32x32x16_bf16(pa.s, vf.s, o[df], 0, 0, 0);
  }
}

__global__ __launch_bounds__(512, 2) void attn_fused(
    const float *__restrict__ Qg, const float *__restrict__ Kg,
    const float *__restrict__ Vg, float *__restrict__ Og, float *__restrict__ Ag) {
  const int b    = blockIdx.x;
  const int qt   = blockIdx.y;
  const int tid  = threadIdx.x;
  const int wid  = tid >> 6;
  const int lane = tid & 63;
  const int l31  = lane & 31;
  const int h    = lane >> 5;

  // K tile row-major [64][128] bf16, swizzled: idx = j*128 + (d ^ ((j&15)<<3))
  // V^T tile [128][64] bf16, swizzled:        idx = d*64  + (j ^ ((d&15)<<2))
  __shared__ __align__(16) unsigned short Kl[KBLK * DDIM];
  __shared__ __align__(16) unsigned short VT[DDIM * KBLK];

  const int q0  = qt * QBLK;
  const int myq = q0 + wid * QW + l31;

  // ---- Q fragments in registers: Q[myq][kk*16 + h*8 + 0..7] ----
  short8 qreg[8];
  {
    const float *qp = Qg + ((size_t)(b * NQ + myq)) * DDIM;
#pragma unroll
    for (int kk = 0; kk < 8; kk++) {
      const int d0 = kk * 16 + h * 8;
      f32x4 x = *(const f32x4 *)(qp + d0);
      f32x4 y = *(const f32x4 *)(qp + d0 + 4);
      short8 t;
      t[0] = f2b(x[0]); t[1] = f2b(x[1]); t[2] = f2b(x[2]); t[3] = f2b(x[3]);
      t[4] = f2b(y[0]); t[5] = f2b(y[1]); t[6] = f2b(y[2]); t[7] = f2b(y[3]);
      qreg[kk] = t;
    }
  }

  const float *kb = Kg + (size_t)b * NQ * DDIM;
  const float *vb = Vg + (size_t)b * NQ * DDIM;

  // staging coords: 512 threads cover a 64x128 fp32 tile with 4 float4 each
  const int sc = tid & 31;          // d-chunk (x4 floats)
  const int kg = tid >> 5;          // 0..15 -> K rows kg*4 + i
  const int sh = (tid >> 5) & 1;
  const int sw = tid >> 6;
  const int vr0 = sw * 8 + sh * 4;  // V rows vr0 + i (4x4 transpose block)

  // ================= PASS A: row sums of exp =================
  float sum = 0.0f;
  f32x4 kst[4];
  {
    const float *p = kb + (size_t)(kg * 4) * DDIM + sc * 4;
#pragma unroll
    for (int i = 0; i < 4; i++) kst[i] = *(const f32x4 *)(p + i * DDIM);
  }
  for (int t = 0; t < NT; t++) {
    __syncthreads();
#pragma unroll
    for (int i = 0; i < 4; i++) {   // write K tile t to LDS (bf16, swizzled)
      const int jr = kg * 4 + i;
      us4 wv; wv[0] = f2b(kst[i][0]); wv[1] = f2b(kst[i][1]);
      wv[2] = f2b(kst[i][2]); wv[3] = f2b(kst[i][3]);
      *(us4 *)&Kl[jr * 128 + ((sc * 4) ^ ((jr & 15) << 3))] = wv;
    }
    if (t + 1 < NT) {               // prefetch next K tile into regs
      const float *p = kb + (size_t)((t + 1) * KBLK + kg * 4) * DDIM + sc * 4;
#pragma unroll
      for (int i = 0; i < 4; i++) kst[i] = *(const f32x4 *)(p + i * DDIM);
    }
    __syncthreads();
    f32x16 s0 = zero16(), s1 = zero16();
#pragma unroll
    for (int kk = 0; kk < 8; kk++) {
      const int dsw = (kk * 16 + h * 8) ^ ((l31 & 15) << 3);
      short8 a0 = *(const short8 *)&Kl[(l31) * 128 + dsw];
      short8 a1 = *(const short8 *)&Kl[(32 + l31) * 128 + dsw];
      s0 = __builtin_amdgcn_mfma_f32_32x32x16_bf16(a0, qreg[kk], s0, 0, 0, 0);
      s1 = __builtin_amdgcn_mfma_f32_32x32x16_bf16(a1, qreg[kk], s1, 0, 0, 0);
    }
#pragma unroll
    for (int r = 0; r < 16; r++) {
      sum += __builtin_exp2f(s0[r] * SEXP);
      sum += __builtin_exp2f(s1[r] * SEXP);
    }
  }
  sum += __shfl_xor(sum, 32, 64);   // partner half holds complementary j's
  const float rl = 1.0f / sum;

  // ================= PASS B: attn write + PV =================
  f32x16 o[4] = {zero16(), zero16(), zero16(), zero16()};
  f32x4 vst[4];
  {
    const float *p = kb + (size_t)(kg * 4) * DDIM + sc * 4;
#pragma unroll
    for (int i = 0; i < 4; i++) kst[i] = *(const f32x4 *)(p + i * DDIM);
    const float *pv = vb + (size_t)(vr0) * DDIM + sc * 4;
#pragma unroll
    for (int i = 0; i < 4; i++) vst[i] = *(const f32x4 *)(pv + i * DDIM);
  }
  for (int t = 0; t < NT; t++) {
    __syncthreads();
#pragma unroll
    for (int i = 0; i < 4; i++) {   // K tile
      const int jr = kg * 4 + i;
      us4 wv; wv[0] = f2b(kst[i][0]); wv[1] = f2b(kst[i][1]);
      wv[2] = f2b(kst[i][2]); wv[3] = f2b(kst[i][3]);
      *(us4 *)&Kl[jr * 128 + ((sc * 4) ^ ((jr & 15) << 3))] = wv;
    }
#pragma unroll
    for (int dd = 0; dd < 4; dd++) { // V tile: 4x4 in-register transpose -> VT
      const int dp = sc * 4 + dd;
      us4 wv; wv[0] = f2b(vst[0][dd]); wv[1] = f2b(vst[1][dd]);
      wv[2] = f2b(vst[2][dd]); wv[3] = f2b(vst[3][dd]);
      *(us4 *)&VT[dp * 64 + (vr0 ^ ((dp & 15) << 2))] = wv;
    }
    if (t + 1 < NT) {
      const float *p = kb + (size_t)((t + 1) * KBLK + kg * 4) * DDIM + sc * 4;
#pragma unroll
      for (int i = 0; i < 4; i++) kst[i] = *(const f32x4 *)(p + i * DDIM);
      const float *pv = vb + (size_t)((t + 1) * KBLK + vr0) * DDIM + sc * 4;
#pragma unroll
      for (int i = 0; i < 4; i++) vst[i] = *(const f32x4 *)(pv + i * DDIM);
    }
    __syncthreads();
    f32x16 s0 = zero16(), s1 = zero16();
#pragma unroll
    for (int kk = 0; kk < 8; kk++) {
      const int dsw = (kk * 16 + h * 8) ^ ((l31 & 15) << 3);
      short8 a0 = *(const short8 *)&Kl[(l31) * 128 + dsw];
      short8 a1 = *(const short8 *)&Kl[(32 + l31) * 128 + dsw];
      s0 = __builtin_amdgcn_mfma_f32_32x32x16_bf16(a0, qreg[kk], s0, 0, 0, 0);
      s1 = __builtin_amdgcn_mfma_f32_32x32x16_bf16(a1, qreg[kk], s1, 0, 0, 0);
    }
    float e0[16], e1[16];
#pragma unroll
    for (int r = 0; r < 16; r++) {
      e0[r] = __builtin_exp2f(s0[r] * SEXP) * rl;
      e1[r] = __builtin_exp2f(s1[r] * SEXP) * rl;
    }
    // normalized P -> global attn (nontemporal: keep 537MB stream out of LLC)
    {
      float *arow = Ag + ((size_t)(b * NQ + myq)) * NQ + t * KBLK;
#pragma unroll
      for (int g = 0; g < 4; g++) {
        f32x4 p0 = {e0[4 * g + 0], e0[4 * g + 1], e0[4 * g + 2], e0[4 * g + 3]};
        f32x4 p1 = {e1[4 * g + 0], e1[4 * g + 1], e1[4 * g + 2], e1[4 * g + 3]};
        __builtin_nontemporal_store(p0, (f32x4 *)(arow + 8 * g + 4 * h));
        __builtin_nontemporal_store(p1, (f32x4 *)(arow + 32 + 8 * g + 4 * h));
      }
    }
    // PV accumulate: tt = k-step (16 j's each)
    pv_step<0>(e0, 0, l31, h, VT, o);
    pv_step<8>(e0, 1, l31, h, VT, o);
    pv_step<0>(e1, 2, l31, h, VT, o);
    pv_step<8>(e1, 3, l31, h, VT, o);
  }

  // ---- write O: o[df][r] = O[q0 + wid*32 + (r&3)+8*(r>>2)+4h][df*32 + l31]
#pragma unroll
  for (int df = 0; df < 4; df++) {
#pragma unroll
    for (int r = 0; r < 16; r++) {
      const int qq = (r & 3) + 8 * (r >> 2) + 4 * h;
      float *op = Og + ((size_t)(b * NQ + q0 + wid * QW + qq)) * DDIM + df * 32 + l31;
      __builtin_nontemporal_store(o[df][r], op);
    }
  }
}

extern "C" void kernel_launch(void *const *d_in, const int *in_sizes, int n_in,
                              void *d_out, int out_size, void *d_ws, size_t ws_size,
                              hipStream_t stream) {
  const float *q = (const float *)d_in[0];
  const float *k = (const float *)d_in[1];
  const float *v = (const float *)d_in[2];
  float *outO = (float *)d_out;
  float *outA = outO + (size_t)NB * NQ * DDIM;   // tuple: (output, attn)
  dim3 grid(NB, NQ / QBLK);                       // batch-major -> XCD = b%8
  attn_fused<<<grid, dim3(512), 0, stream>>>(q, k, v, outO, outA);
}